// Round 6
// baseline (274.844 us; speedup 1.0000x reference)
//
#include <hip/hip_runtime.h>
#include <math.h>

// Problem constants
constexpr int NROI = 2048;  // N
constexpr int CDIM = 1024;  // C
constexpr int NG   = 16;    // groups
constexpr int DH   = 64;    // per-group dim

typedef __attribute__((ext_vector_type(8))) short short8;    // 8 bf16 (4 VGPRs)
typedef __attribute__((ext_vector_type(4))) float floatx4;   // MFMA C/D frag

#define MFMA_BF16(a, b, c) __builtin_amdgcn_mfma_f32_16x16x32_bf16((a), (b), (c), 0, 0, 0)

// fp32 -> bf16 round-to-nearest-even
__device__ __forceinline__ short f2bf(float f) {
  unsigned u = __float_as_uint(f);
  unsigned r = 0x7fffu + ((u >> 16) & 1u);
  return (short)((u + r) >> 16);
}
__device__ __forceinline__ unsigned pack2(float a, float b) {
  return (unsigned)(unsigned short)f2bf(a) | ((unsigned)(unsigned short)f2bf(b) << 16);
}
// RTZ pack for P (P>=0, normalized away by softmax ratio)
__device__ __forceinline__ unsigned pack_rtz(float a, float b) {
  return (__float_as_uint(a) >> 16) | (__float_as_uint(b) & 0xFFFF0000u);
}

// async global->LDS, 16B per lane; LDS dest = wave-uniform base + lane*16
typedef __attribute__((address_space(1))) void GV;
typedef __attribute__((address_space(3))) void LV;
__device__ __forceinline__ void gl2lds16(const void* g, void* l) {
  __builtin_amdgcn_global_load_lds((GV*)g, (LV*)l, 16, 0, 0);
}

// fine-grained waitcnt: vmcnt(N), lgkm/exp untouched.
// imm16: vmcnt[3:0]=b[3:0], expcnt=b[6:4], lgkmcnt=b[11:8], vmcnt[5:4]=b[15:14]
__device__ __forceinline__ void waitcnt_vm16() { __builtin_amdgcn_s_waitcnt(0x4F70); }
__device__ __forceinline__ void waitcnt_vm12() { __builtin_amdgcn_s_waitcnt(0x0F7C); }
__device__ __forceinline__ void sbar() { __builtin_amdgcn_sched_barrier(0); }

// bf16 relu on a packed short8 (sign-bit based; exact)
__device__ __forceinline__ short8 brelu(short8 v) {
  union { short8 s; unsigned u[4]; } x; x.s = v;
#pragma unroll
  for (int i = 0; i < 4; ++i) {
    unsigned m = (x.u[i] >> 15) & 0x10001u;
    x.u[i] &= ~(m * 0xFFFFu);
  }
  return x.s;
}

// ---------------- fused: fp32->bf16 conversions AND ln(iou+1e-6) bias matrix ----------------
__global__ __launch_bounds__(256) void conv_iou(
    const float* __restrict__ in_x, const float* __restrict__ W0,
    const float* __restrict__ W1, const float* __restrict__ Wout,
    const float* __restrict__ rois,
    short* __restrict__ xin_b, short* __restrict__ W0b,
    short* __restrict__ W1b, short* __restrict__ Woutb,
    unsigned short* __restrict__ biasln)
{
  const int b = blockIdx.x;
  if (b < 2048) {
    const int i = b * 256 + threadIdx.x;   // float4 units
    {
      const float4 v = ((const float4*)in_x)[i];
      uint2 u; u.x = pack2(v.x, v.y); u.y = pack2(v.z, v.w);
      ((uint2*)xin_b)[i] = u;
    }
    if (i < 262144) {
      float4 v = ((const float4*)W0)[i];
      uint2 u; u.x = pack2(v.x, v.y); u.y = pack2(v.z, v.w);
      ((uint2*)W0b)[i] = u;
      v = ((const float4*)W1)[i];
      u.x = pack2(v.x, v.y); u.y = pack2(v.z, v.w);
      ((uint2*)W1b)[i] = u;
      v = ((const float4*)Wout)[i];
      u.x = pack2(v.x, v.y); u.y = pack2(v.z, v.w);
      ((uint2*)Woutb)[i] = u;
    }
  } else {
    const int p = (b - 2048) * 256 + threadIdx.x;   // pair index
    const int q = p >> 11, k = p & 2047;            // q uniform per block
    const float qx1 = rois[q * 5 + 1], qy1 = rois[q * 5 + 2];
    const float qx2 = rois[q * 5 + 3], qy2 = rois[q * 5 + 4];
    const float qa = (qx2 - qx1 + 1.f) * (qy2 - qy1 + 1.f);
    const float kx1 = rois[k * 5 + 1], ky1 = rois[k * 5 + 2];
    const float kx2 = rois[k * 5 + 3], ky2 = rois[k * 5 + 4];
    const float ka = (kx2 - kx1 + 1.f) * (ky2 - ky1 + 1.f);
    float iw = fminf(qx2, kx2) - fmaxf(qx1, kx1) + 1.f;
    float ih = fminf(qy2, ky2) - fmaxf(qy1, ky1) + 1.f;
    iw = fmaxf(iw, 0.f); ih = fmaxf(ih, 0.f);
    const float inter = iw * ih;
    const float iou = inter / (qa + ka - inter);
    biasln[p] = (unsigned short)f2bf(__logf(iou + 1e-6f));
  }
}

// ---------------- wave-private barrier-free GEMM: 64x32 tile, 1 wave/block ----------------
// C = [relu](A) @ B^T (+bias). FUSED=1: grid.x 0..63, bx<32 -> W0 half (relu,
// bias, row-major out), bx>=32 -> Wout half (transposed out, no bias/relu).
// No __syncthreads anywhere: double-buffered global_load_lds + s_waitcnt vmcnt(12)
// keeps the prefetch batch in flight across iterations (never drains to 0).
template <int FUSED>
__global__ __launch_bounds__(64) void gemm_wp(
    const short* __restrict__ A, const short* __restrict__ Ba,
    const short* __restrict__ Bb, const float* __restrict__ bias,
    short* __restrict__ outRM, short* __restrict__ outTR)
{
  const int lane = threadIdx.x;
  const int c = lane & 15, Q = lane >> 4;
  const int rlo = c, khi = Q * 8;
  const int row0 = blockIdx.y * 64;
  int colb; const short* B; bool doRelu, toTR;
  if (FUSED) {
    const int bx = blockIdx.x;
    const bool isW0 = bx < 32;
    colb = (bx & 31) * 32;
    B = isW0 ? Ba : Bb;
    doRelu = isW0; toTR = !isW0;
  } else {
    colb = blockIdx.x * 32; B = Ba; doRelu = true; toTR = false;
  }

  __shared__ short As[2][8 * 512];
  __shared__ short Bs[2][4 * 512];

  floatx4 acc[4][2];
#pragma unroll
  for (int i = 0; i < 4; ++i)
#pragma unroll
    for (int j = 0; j < 2; ++j) acc[i][j] = (floatx4){0.f, 0.f, 0.f, 0.f};

  // stage k0=0 into buffer 0
#pragma unroll
  for (int f = 0; f < 8; ++f)
    gl2lds16(A + (size_t)(row0 + (f >> 1) * 16 + rlo) * CDIM + (f & 1) * 32 + khi,
             &As[0][f * 512]);
#pragma unroll
  for (int f = 0; f < 4; ++f)
    gl2lds16(B + (size_t)(colb + (f >> 1) * 16 + rlo) * CDIM + (f & 1) * 32 + khi,
             &Bs[0][f * 512]);

  for (int it = 0; it < 16; ++it) {
    const int p = it & 1;
    const int k1 = (it + 1) * 64;  // last iter reads past K into adjacent ws (junk, unused)
    sbar();
#pragma unroll
    for (int f = 0; f < 8; ++f)
      gl2lds16(A + (size_t)(row0 + (f >> 1) * 16 + rlo) * CDIM + k1 + (f & 1) * 32 + khi,
               &As[1 - p][f * 512]);
#pragma unroll
    for (int f = 0; f < 4; ++f)
      gl2lds16(B + (size_t)(colb + (f >> 1) * 16 + rlo) * CDIM + k1 + (f & 1) * 32 + khi,
               &Bs[1 - p][f * 512]);
    waitcnt_vm12();   // current tile (oldest 12) done; prefetch (newest 12) in flight
    sbar();

    short8 af[8], bf[4];
    if (doRelu) {
#pragma unroll
      for (int f = 0; f < 8; ++f)
        af[f] = brelu(*(const short8*)&As[p][f * 512 + lane * 8]);
    } else {
#pragma unroll
      for (int f = 0; f < 8; ++f)
        af[f] = *(const short8*)&As[p][f * 512 + lane * 8];
    }
#pragma unroll
    for (int f = 0; f < 4; ++f) bf[f] = *(const short8*)&Bs[p][f * 512 + lane * 8];
#pragma unroll
    for (int kh = 0; kh < 2; ++kh)
#pragma unroll
      for (int i = 0; i < 4; ++i)
#pragma unroll
        for (int j = 0; j < 2; ++j)
          acc[i][j] = MFMA_BF16(af[i * 2 + kh], bf[j * 2 + kh], acc[i][j]);
  }

  if (!toTR) {
    const float bj0 = bias[colb + c];
    const float bj1 = bias[colb + 16 + c];
#pragma unroll
    for (int i = 0; i < 4; ++i)
#pragma unroll
      for (int r = 0; r < 4; ++r) {
        const int row = row0 + i * 16 + Q * 4 + r;
        outRM[(size_t)row * CDIM + colb + c]      = f2bf(acc[i][0][r] + bj0);
        outRM[(size_t)row * CDIM + colb + 16 + c] = f2bf(acc[i][1][r] + bj1);
      }
  } else {
#pragma unroll
    for (int i = 0; i < 4; ++i)
#pragma unroll
      for (int j = 0; j < 2; ++j) {
        unsigned long long u =
            (unsigned long long)pack2(acc[i][j][0], acc[i][j][1]) |
            ((unsigned long long)pack2(acc[i][j][2], acc[i][j][3]) << 32);
        *(unsigned long long*)&outTR[(size_t)(colb + j * 16 + c) * NROI +
                                     row0 + i * 16 + Q * 4] = u;
      }
  }
}

// ---------------- wave-private barrier-free flash attention ----------------
// S' = K Q^T (operands swapped): C-layout rows = keys -> consecutive regs =
// consecutive keys, so the P C->A transform is 4 ds_write_b64 per subtile and
// bias reads are row-major uint2. 32 q-rows/wave (2 subtiles) halve per-q K/V
// LDS reads. P = exp(s/8 + ln(iou+1e-6)), no running max; lsum is one scalar.
__global__ __launch_bounds__(64) void attn_wp(
    const short* __restrict__ Xb,              // (N,C) bf16 embedded x
    const short* __restrict__ ZTb,             // (C,N) bf16 V, transposed
    const unsigned short* __restrict__ biasln, // (N,N) bf16 ln(iou+1e-6)
    const float* __restrict__ bout,
    float* __restrict__ Out)
{
  const int g = blockIdx.y, q0 = blockIdx.x * 32;
  const int lane = threadIdx.x;
  const int c = lane & 15, Q = lane >> 4;
  const int rlo = c, khi = Q * 8;
  const int goff = g * DH;

  __shared__ short KT[2][8 * 512];
  __shared__ short VT[2][8 * 512];
  __shared__ short PT[2][1024];    // per-subtile P A-frags (wave-private, in-order reuse)

  // Q B-frags: B[n=q][k], n = lane&15, k = (lane>>4)*8+j
  short8 qf[2][2];
#pragma unroll
  for (int s = 0; s < 2; ++s)
#pragma unroll
    for (int h = 0; h < 2; ++h)
      qf[s][h] = *(const short8*)(Xb + (size_t)(q0 + s * 16 + c) * CDIM + goff +
                                  h * 32 + Q * 8);

  floatx4 oc[2][4];
#pragma unroll
  for (int s = 0; s < 2; ++s)
#pragma unroll
    for (int dt = 0; dt < 4; ++dt) oc[s][dt] = (floatx4){0.f, 0.f, 0.f, 0.f};
  float ls[2] = {0.f, 0.f};

  // stage tile 0 into buffer 0
#pragma unroll
  for (int f = 0; f < 8; ++f) {
    gl2lds16(Xb + (size_t)((f >> 1) * 16 + rlo) * CDIM + goff + (f & 1) * 32 + khi,
             &KT[0][f * 512]);
    gl2lds16(ZTb + (size_t)(goff + (f >> 1) * 16 + rlo) * NROI + (f & 1) * 32 + khi,
             &VT[0][f * 512]);
  }

  for (int it = 0; it < 32; ++it) {
    const int p = it & 1;
    const int m0 = it * 64, m1 = m0 + 64;  // last-iter prefetch reads ws junk (unused)
    sbar();
#pragma unroll
    for (int f = 0; f < 8; ++f) {
      gl2lds16(Xb + (size_t)(m1 + (f >> 1) * 16 + rlo) * CDIM + goff + (f & 1) * 32 + khi,
               &KT[1 - p][f * 512]);
      gl2lds16(ZTb + (size_t)(goff + (f >> 1) * 16 + rlo) * NROI + m1 + (f & 1) * 32 + khi,
               &VT[1 - p][f * 512]);
    }
    waitcnt_vm16();  // current K/V ready; the 16 prefetch loads stay in flight
    sbar();

    short8 kf[8];
#pragma unroll
    for (int f = 0; f < 8; ++f)
      kf[f] = *(const short8*)&KT[p][f * 512 + lane * 8];

    uint2 bb[2][4];
#pragma unroll
    for (int s = 0; s < 2; ++s)
#pragma unroll
      for (int ct = 0; ct < 4; ++ct)
        bb[s][ct] = *(const uint2*)(biasln + (size_t)(q0 + s * 16 + c) * NROI +
                                    m0 + ct * 16 + Q * 4);

#pragma unroll
    for (int s = 0; s < 2; ++s) {
      floatx4 sc[4];
#pragma unroll
      for (int ct = 0; ct < 4; ++ct) {
        floatx4 z = (floatx4){0.f, 0.f, 0.f, 0.f};
        z = MFMA_BF16(kf[ct * 2 + 0], qf[s][0], z);   // A=K, B=Q -> rows=keys
        z = MFMA_BF16(kf[ct * 2 + 1], qf[s][1], z);
        sc[ct] = z;
      }
#pragma unroll
      for (int ct = 0; ct < 4; ++ct) {
        const unsigned ux = bb[s][ct].x, uy = bb[s][ct].y;
        sc[ct][0] = __expf(fmaf(sc[ct][0], 0.125f, __uint_as_float(ux << 16)));
        sc[ct][1] = __expf(fmaf(sc[ct][1], 0.125f, __uint_as_float(ux & 0xFFFF0000u)));
        sc[ct][2] = __expf(fmaf(sc[ct][2], 0.125f, __uint_as_float(uy << 16)));
        sc[ct][3] = __expf(fmaf(sc[ct][3], 0.125f, __uint_as_float(uy & 0xFFFF0000u)));
        ls[s] += sc[ct][0] + sc[ct][1] + sc[ct][2] + sc[ct][3];
        // pack 4 consecutive keys -> one b64 into P A-frag layout
        const int h  = (4 * ct + Q) >> 3;           // key half (0..1)
        const int o  = (2 * ct + (Q >> 1)) & 3;     // key octet within half
        const int j0 = (Q & 1) * 4;                 // offset within octet
        const unsigned long long u =
            (unsigned long long)pack_rtz(sc[ct][0], sc[ct][1]) |
            ((unsigned long long)pack_rtz(sc[ct][2], sc[ct][3]) << 32);
        *(unsigned long long*)&PT[s][h * 512 + (c + 16 * o) * 8 + j0] = u;
      }
    }

    short8 vf[8];
#pragma unroll
    for (int f = 0; f < 8; ++f)
      vf[f] = *(const short8*)&VT[p][f * 512 + lane * 8];
#pragma unroll
    for (int s = 0; s < 2; ++s) {
      const short8 pa0 = *(const short8*)&PT[s][lane * 8];
      const short8 pa1 = *(const short8*)&PT[s][512 + lane * 8];
#pragma unroll
      for (int dt = 0; dt < 4; ++dt) {
        oc[s][dt] = MFMA_BF16(pa0, vf[dt * 2 + 0], oc[s][dt]);
        oc[s][dt] = MFMA_BF16(pa1, vf[dt * 2 + 1], oc[s][dt]);
      }
    }
  }

  // lsum: reduce across the 4 quads (same col), then redistribute to C-rows
#pragma unroll
  for (int s = 0; s < 2; ++s) {
    float v = ls[s];
    v += __shfl_xor(v, 16);
    v += __shfl_xor(v, 32);
    ls[s] = v;
  }
#pragma unroll
  for (int s = 0; s < 2; ++s) {
    float inv[4];
#pragma unroll
    for (int r = 0; r < 4; ++r)
      inv[r] = __builtin_amdgcn_rcpf(__shfl(ls[s], Q * 4 + r));
#pragma unroll
    for (int dt = 0; dt < 4; ++dt) {
      const float bo = bout[goff + dt * 16 + c];
#pragma unroll
      for (int r = 0; r < 4; ++r)
        Out[(size_t)(q0 + s * 16 + Q * 4 + r) * CDIM + goff + dt * 16 + c] =
            oc[s][dt][r] * inv[r] + bo;
    }
  }
}

extern "C" void kernel_launch(void* const* d_in, const int* in_sizes, int n_in,
                              void* d_out, int out_size, void* d_ws, size_t ws_size,
                              hipStream_t stream) {
  const float* in_x = (const float*)d_in[0];
  const float* rois = (const float*)d_in[1];
  const float* W0   = (const float*)d_in[2];
  const float* b0   = (const float*)d_in[3];
  const float* W1   = (const float*)d_in[4];
  const float* b1   = (const float*)d_in[5];
  const float* Wout = (const float*)d_in[6];  // (G,D,C) flat == (C,C) row-major
  const float* bout = (const float*)d_in[7];
  char* w8 = (char*)d_ws;

  // ws layout (22 MB):
  //   [0,4M)   xin_b (bf16 x) -> xb (gemm1 out; xin_b dead after gemm_wp<1>)
  //   [4,6M)   W0b   [6,8M) W1b   [8,10M) Woutb
  //   [10,14M) zT (bf16 V^T)
  //   [14,22M) biasln (bf16 ln(iou+1e-6))
  // t0b (bf16 gemm0 out) lives in d_out; attn overwrites d_out with final fp32.
  // NOTE: last-iteration prefetches intentionally read ~200B past each operand;
  // all land inside d_ws/d_out allocations (values unused).
  short* xin_b = (short*)w8;
  short* W0b   = (short*)(w8 + ((size_t)4 << 20));
  short* W1b   = (short*)(w8 + ((size_t)6 << 20));
  short* Woutb = (short*)(w8 + ((size_t)8 << 20));
  short* zT    = (short*)(w8 + ((size_t)10 << 20));
  unsigned short* biasln = (unsigned short*)(w8 + ((size_t)14 << 20));
  short* xb  = xin_b;
  short* t0b = (short*)d_out;

  // 1) conversions + ln-iou bias
  conv_iou<<<2048 + 16384, 256, 0, stream>>>(in_x, W0, W1, Wout, rois,
                                             xin_b, W0b, W1b, Woutb, biasln);
  // 2) fused wave-private GEMM: t0 = relu(x)@W0^T+b0 and zT = (x@Wout^T)^T
  gemm_wp<1><<<dim3(64, 32), 64, 0, stream>>>(xin_b, W0b, Woutb, b0, t0b, zT);
  // 3) xb = relu(t0)@W1^T + b1
  gemm_wp<0><<<dim3(32, 32), 64, 0, stream>>>(t0b, W1b, W1b, b1, xb, nullptr);
  // 4) wave-private barrier-free flash attention
  attn_wp<<<dim3(NROI / 32, NG), 64, 0, stream>>>(xb, zT, biasln, bout,
                                                  (float*)d_out);
}

// Round 7
// 223.824 us; speedup vs baseline: 1.2279x; 1.2279x over previous
//
#include <hip/hip_runtime.h>
#include <math.h>

// Problem constants
constexpr int NROI = 2048;  // N
constexpr int CDIM = 1024;  // C
constexpr int NG   = 16;    // groups
constexpr int DH   = 64;    // per-group dim

typedef __attribute__((ext_vector_type(8))) short short8;    // 8 bf16 (4 VGPRs)
typedef __attribute__((ext_vector_type(4))) float floatx4;   // MFMA C/D frag

#define MFMA_BF16(a, b, c) __builtin_amdgcn_mfma_f32_16x16x32_bf16((a), (b), (c), 0, 0, 0)

// fp32 -> bf16 round-to-nearest-even
__device__ __forceinline__ short f2bf(float f) {
  unsigned u = __float_as_uint(f);
  unsigned r = 0x7fffu + ((u >> 16) & 1u);
  return (short)((u + r) >> 16);
}
__device__ __forceinline__ unsigned pack2(float a, float b) {
  return (unsigned)(unsigned short)f2bf(a) | ((unsigned)(unsigned short)f2bf(b) << 16);
}
// RTZ pack for P (P>=0, normalized away by the softmax ratio)
__device__ __forceinline__ unsigned pack_rtz(float a, float b) {
  return (__float_as_uint(a) >> 16) | (__float_as_uint(b) & 0xFFFF0000u);
}

// async global->LDS, 16B per lane; LDS dest = wave-uniform base + lane*16
typedef __attribute__((address_space(1))) void GV;
typedef __attribute__((address_space(3))) void LV;
__device__ __forceinline__ void gl2lds16(const void* g, void* l) {
  __builtin_amdgcn_global_load_lds((GV*)g, (LV*)l, 16, 0, 0);
}

// bf16 relu on a packed short8 (sign-bit based; exact)
__device__ __forceinline__ short8 brelu(short8 v) {
  union { short8 s; unsigned u[4]; } x; x.s = v;
#pragma unroll
  for (int i = 0; i < 4; ++i) {
    unsigned m = (x.u[i] >> 15) & 0x10001u;
    x.u[i] &= ~(m * 0xFFFFu);
  }
  return x.s;
}

// ---------------- fused: fp32->bf16 conversions AND ln(iou+1e-6) bias matrix ----------------
__global__ __launch_bounds__(256) void conv_iou(
    const float* __restrict__ in_x, const float* __restrict__ W0,
    const float* __restrict__ W1, const float* __restrict__ Wout,
    const float* __restrict__ rois,
    short* __restrict__ xin_b, short* __restrict__ W0b,
    short* __restrict__ W1b, short* __restrict__ Woutb,
    unsigned short* __restrict__ biasln)
{
  const int b = blockIdx.x;
  if (b < 2048) {
    const int i = b * 256 + threadIdx.x;   // float4 units
    {
      const float4 v = ((const float4*)in_x)[i];
      uint2 u; u.x = pack2(v.x, v.y); u.y = pack2(v.z, v.w);
      ((uint2*)xin_b)[i] = u;
    }
    if (i < 262144) {
      float4 v = ((const float4*)W0)[i];
      uint2 u; u.x = pack2(v.x, v.y); u.y = pack2(v.z, v.w);
      ((uint2*)W0b)[i] = u;
      v = ((const float4*)W1)[i];
      u.x = pack2(v.x, v.y); u.y = pack2(v.z, v.w);
      ((uint2*)W1b)[i] = u;
      v = ((const float4*)Wout)[i];
      u.x = pack2(v.x, v.y); u.y = pack2(v.z, v.w);
      ((uint2*)Woutb)[i] = u;
    }
  } else {
    const int p = (b - 2048) * 256 + threadIdx.x;   // pair index
    const int q = p >> 11, k = p & 2047;            // q uniform per block
    const float qx1 = rois[q * 5 + 1], qy1 = rois[q * 5 + 2];
    const float qx2 = rois[q * 5 + 3], qy2 = rois[q * 5 + 4];
    const float qa = (qx2 - qx1 + 1.f) * (qy2 - qy1 + 1.f);
    const float kx1 = rois[k * 5 + 1], ky1 = rois[k * 5 + 2];
    const float kx2 = rois[k * 5 + 3], ky2 = rois[k * 5 + 4];
    const float ka = (kx2 - kx1 + 1.f) * (ky2 - ky1 + 1.f);
    float iw = fminf(qx2, kx2) - fmaxf(qx1, kx1) + 1.f;
    float ih = fminf(qy2, ky2) - fmaxf(qy1, ky1) + 1.f;
    iw = fmaxf(iw, 0.f); ih = fmaxf(ih, 0.f);
    const float inter = iw * ih;
    const float iou = inter / (qa + ka - inter);
    biasln[p] = (unsigned short)f2bf(__logf(iou + 1e-6f));
  }
}

// ---------------- double-buffered 128x128 fused GEMM (GEMM0 + GEMM2) ----------------
// blockIdx.x < 8: t0 = relu(x)@W0^T + b0 (row-major bf16 out).
// blockIdx.x >= 8: zT = (x@Wout^T)^T (bf16, C x N).
// m97 pipeline: stage(k+1) issued BEFORE compute(k); one barrier per iter.
__global__ __launch_bounds__(256) void gemm_fused(
    const short* __restrict__ A, const short* __restrict__ BW0,
    const short* __restrict__ BWout, const float* __restrict__ b0,
    short* __restrict__ t0b, short* __restrict__ zT)
{
  __shared__ short As[2][16 * 512];
  __shared__ short Bs[2][16 * 512];
  const int t = threadIdx.x, w = t >> 6, lane = t & 63;
  const int wm = w >> 1, wn = w & 1;
  const int row0 = blockIdx.y * 128;
  const int bx = blockIdx.x;
  const bool isW0 = bx < 8;
  const int col0 = (bx & 7) * 128;
  const short* B = isW0 ? BW0 : BWout;
  const int rlo = lane & 15, khi = (lane >> 4) * 8;

  floatx4 acc[4][4];
#pragma unroll
  for (int i = 0; i < 4; ++i)
#pragma unroll
    for (int j = 0; j < 4; ++j) acc[i][j] = (floatx4){0.f, 0.f, 0.f, 0.f};

  // stage k=0 into buffer 0 (wave w stages frags w*4..w*4+3 of each operand)
#pragma unroll
  for (int q = 0; q < 4; ++q) {
    const int f = w * 4 + q, rt = f >> 1, kh = f & 1;
    gl2lds16(A + (size_t)(row0 + rt * 16 + rlo) * CDIM + kh * 32 + khi, &As[0][f * 512]);
    gl2lds16(B + (size_t)(col0 + rt * 16 + rlo) * CDIM + kh * 32 + khi, &Bs[0][f * 512]);
  }
  __syncthreads();

  for (int it = 0; it < 16; ++it) {
    const int p = it & 1;
    if (it < 15) {                    // prefetch next K-tile while computing this one
      const int k1 = (it + 1) * 64;
#pragma unroll
      for (int q = 0; q < 4; ++q) {
        const int f = w * 4 + q, rt = f >> 1, kh = f & 1;
        gl2lds16(A + (size_t)(row0 + rt * 16 + rlo) * CDIM + k1 + kh * 32 + khi,
                 &As[1 - p][f * 512]);
        gl2lds16(B + (size_t)(col0 + rt * 16 + rlo) * CDIM + k1 + kh * 32 + khi,
                 &Bs[1 - p][f * 512]);
      }
    }
#pragma unroll
    for (int kh = 0; kh < 2; ++kh) {
      short8 a[4], bf[4];
#pragma unroll
      for (int i = 0; i < 4; ++i) {
        a[i] = *(const short8*)&As[p][((wm * 4 + i) * 2 + kh) * 512 + lane * 8];
        if (isW0) a[i] = brelu(a[i]);
      }
#pragma unroll
      for (int j = 0; j < 4; ++j)
        bf[j] = *(const short8*)&Bs[p][((wn * 4 + j) * 2 + kh) * 512 + lane * 8];
#pragma unroll
      for (int i = 0; i < 4; ++i)
#pragma unroll
        for (int j = 0; j < 4; ++j)
          acc[i][j] = MFMA_BF16(a[i], bf[j], acc[i][j]);
    }
    __syncthreads();   // readers of buf p done; drains prefetch into buf 1-p
  }

  const int colL = lane & 15, qq = lane >> 4;
  if (isW0) {
    float bj[4];
#pragma unroll
    for (int j = 0; j < 4; ++j) bj[j] = b0[col0 + wn * 64 + j * 16 + colL];
#pragma unroll
    for (int i = 0; i < 4; ++i)
#pragma unroll
      for (int j = 0; j < 4; ++j)
#pragma unroll
        for (int r = 0; r < 4; ++r) {
          const int row = row0 + wm * 64 + i * 16 + qq * 4 + r;
          const int cc  = col0 + wn * 64 + j * 16 + colL;
          t0b[(size_t)row * CDIM + cc] = f2bf(acc[i][j][r] + bj[j]);
        }
  } else {
#pragma unroll
    for (int i = 0; i < 4; ++i)
#pragma unroll
      for (int j = 0; j < 4; ++j) {
        unsigned long long u =
            (unsigned long long)pack2(acc[i][j][0], acc[i][j][1]) |
            ((unsigned long long)pack2(acc[i][j][2], acc[i][j][3]) << 32);
        const int cc  = col0 + wn * 64 + j * 16 + colL;
        const int row = row0 + wm * 64 + i * 16 + qq * 4;
        *(unsigned long long*)&zT[(size_t)cc * NROI + row] = u;
      }
  }
}

// ---------------- double-buffered 128x64 GEMM1: xb = relu(t0) @ W1^T + b1 ----------------
__global__ __launch_bounds__(256) void gemm1k(
    const short* __restrict__ A, const short* __restrict__ B,
    const float* __restrict__ bias, short* __restrict__ C)
{
  __shared__ short As[2][16 * 512];
  __shared__ short Bs[2][8 * 512];
  const int t = threadIdx.x, w = t >> 6, lane = t & 63;
  const int wm = w >> 1, wn = w & 1;     // wave quadrant: 64 rows x 32 cols
  const int row0 = blockIdx.y * 128, col0 = blockIdx.x * 64;
  const int rlo = lane & 15, khi = (lane >> 4) * 8;

  floatx4 acc[4][2];
#pragma unroll
  for (int i = 0; i < 4; ++i)
#pragma unroll
    for (int j = 0; j < 2; ++j) acc[i][j] = (floatx4){0.f, 0.f, 0.f, 0.f};

#pragma unroll
  for (int q = 0; q < 4; ++q) {
    const int f = w * 4 + q, rt = f >> 1, kh = f & 1;
    gl2lds16(A + (size_t)(row0 + rt * 16 + rlo) * CDIM + kh * 32 + khi, &As[0][f * 512]);
  }
#pragma unroll
  for (int q = 0; q < 2; ++q) {
    const int f = w * 2 + q, rt = f >> 1, kh = f & 1;
    gl2lds16(B + (size_t)(col0 + rt * 16 + rlo) * CDIM + kh * 32 + khi, &Bs[0][f * 512]);
  }
  __syncthreads();

  for (int it = 0; it < 16; ++it) {
    const int p = it & 1;
    if (it < 15) {
      const int k1 = (it + 1) * 64;
#pragma unroll
      for (int q = 0; q < 4; ++q) {
        const int f = w * 4 + q, rt = f >> 1, kh = f & 1;
        gl2lds16(A + (size_t)(row0 + rt * 16 + rlo) * CDIM + k1 + kh * 32 + khi,
                 &As[1 - p][f * 512]);
      }
#pragma unroll
      for (int q = 0; q < 2; ++q) {
        const int f = w * 2 + q, rt = f >> 1, kh = f & 1;
        gl2lds16(B + (size_t)(col0 + rt * 16 + rlo) * CDIM + k1 + kh * 32 + khi,
                 &Bs[1 - p][f * 512]);
      }
    }
#pragma unroll
    for (int kh = 0; kh < 2; ++kh) {
      short8 a[4], bf[2];
#pragma unroll
      for (int i = 0; i < 4; ++i)
        a[i] = brelu(*(const short8*)&As[p][((wm * 4 + i) * 2 + kh) * 512 + lane * 8]);
#pragma unroll
      for (int j = 0; j < 2; ++j)
        bf[j] = *(const short8*)&Bs[p][((wn * 2 + j) * 2 + kh) * 512 + lane * 8];
#pragma unroll
      for (int i = 0; i < 4; ++i)
#pragma unroll
        for (int j = 0; j < 2; ++j)
          acc[i][j] = MFMA_BF16(a[i], bf[j], acc[i][j]);
    }
    __syncthreads();
  }

  const int colL = lane & 15, qq = lane >> 4;
  float bj[2];
  bj[0] = bias[col0 + wn * 32 + colL];
  bj[1] = bias[col0 + wn * 32 + 16 + colL];
#pragma unroll
  for (int i = 0; i < 4; ++i)
#pragma unroll
    for (int j = 0; j < 2; ++j)
#pragma unroll
      for (int r = 0; r < 4; ++r) {
        const int row = row0 + wm * 64 + i * 16 + qq * 4 + r;
        const int cc  = col0 + wn * 32 + j * 16 + colL;
        C[(size_t)row * CDIM + cc] = f2bf(acc[i][j][r] + bj[j]);
      }
}

// ---------------- MFMA flash attention: K-major S', 32 q/wave, coop dbuf ----------------
// S' = K Q^T (C-layout rows = keys, col = q): P-pack is 8 ds_write_b64/wave-iter,
// bias reads are row-major uint2 (4 keys/load). P = exp(s/8 + ln(iou+1e-6)),
// no running max. 256 thr = 4 waves; each wave owns 32 q (2 subtiles); K/V
// staged cooperatively, double-buffered (prefetch overlaps compute).
__global__ __launch_bounds__(256) void attn3(
    const short* __restrict__ Xb,              // (N,C) bf16 embedded x
    const short* __restrict__ ZTb,             // (C,N) bf16 V, transposed
    const unsigned short* __restrict__ biasln, // (N,N) bf16 ln(iou+1e-6)
    const float* __restrict__ bout,
    float* __restrict__ Out)
{
  const int g = blockIdx.y, q0 = blockIdx.x * 128;
  const int t = threadIdx.x, w = t >> 6, lane = t & 63;
  const int c = lane & 15, Q = lane >> 4;
  const int rlo = c, khi = Q * 8;
  const int goff = g * DH;
  const int qw = q0 + w * 32;    // this wave's 32-q base

  __shared__ short Kf[2][8 * 512];
  __shared__ short Vf[2][8 * 512];
  __shared__ short PT[4][2][1024];   // per-wave, per-subtile P A-frags

  // Q B-frags: B[n=q][k=d]
  short8 qf[2][2];
#pragma unroll
  for (int s = 0; s < 2; ++s)
#pragma unroll
    for (int h = 0; h < 2; ++h)
      qf[s][h] = *(const short8*)(Xb + (size_t)(qw + s * 16 + c) * CDIM + goff +
                                  h * 32 + Q * 8);

  floatx4 oc[2][4];
#pragma unroll
  for (int s = 0; s < 2; ++s)
#pragma unroll
    for (int dt = 0; dt < 4; ++dt) oc[s][dt] = (floatx4){0.f, 0.f, 0.f, 0.f};
  float ls[2] = {0.f, 0.f};

  // stage tile 0 (wave w stages K frags 2w,2w+1 and V frags 2w,2w+1)
#pragma unroll
  for (int kh = 0; kh < 2; ++kh) {
    const int f = w * 2 + kh;
    gl2lds16(Xb + (size_t)(w * 16 + rlo) * CDIM + goff + kh * 32 + khi,
             &Kf[0][f * 512]);
    gl2lds16(ZTb + (size_t)(goff + w * 16 + rlo) * NROI + kh * 32 + khi,
             &Vf[0][f * 512]);
  }
  // bias regs for iter 0: row-major uint2 = 4 consecutive keys for q = row
  uint2 bb[2][4];
#pragma unroll
  for (int s = 0; s < 2; ++s)
#pragma unroll
    for (int ct = 0; ct < 4; ++ct)
      bb[s][ct] = *(const uint2*)(biasln + (size_t)(qw + s * 16 + c) * NROI +
                                  ct * 16 + Q * 4);
  __syncthreads();

  for (int it = 0; it < 32; ++it) {
    const int p = it & 1;
    const int m0 = it * 64;
    uint2 bn[2][4];
    if (it < 31) {     // prefetch next K/V tile + next bias regs
      const int m1 = m0 + 64;
#pragma unroll
      for (int kh = 0; kh < 2; ++kh) {
        const int f = w * 2 + kh;
        gl2lds16(Xb + (size_t)(m1 + w * 16 + rlo) * CDIM + goff + kh * 32 + khi,
                 &Kf[1 - p][f * 512]);
        gl2lds16(ZTb + (size_t)(goff + w * 16 + rlo) * NROI + m1 + kh * 32 + khi,
                 &Vf[1 - p][f * 512]);
      }
#pragma unroll
      for (int s = 0; s < 2; ++s)
#pragma unroll
        for (int ct = 0; ct < 4; ++ct)
          bn[s][ct] = *(const uint2*)(biasln + (size_t)(qw + s * 16 + c) * NROI +
                                      m1 + ct * 16 + Q * 4);
    }

    short8 kf[8];
#pragma unroll
    for (int f = 0; f < 8; ++f)
      kf[f] = *(const short8*)&Kf[p][f * 512 + lane * 8];

#pragma unroll
    for (int s = 0; s < 2; ++s) {
      floatx4 sc[4];
#pragma unroll
      for (int ct = 0; ct < 4; ++ct) {
        floatx4 z = (floatx4){0.f, 0.f, 0.f, 0.f};
        z = MFMA_BF16(kf[ct * 2 + 0], qf[s][0], z);   // A=K, B=Q -> rows=keys
        z = MFMA_BF16(kf[ct * 2 + 1], qf[s][1], z);
        sc[ct] = z;
      }
#pragma unroll
      for (int ct = 0; ct < 4; ++ct) {
        const unsigned ux = bb[s][ct].x, uy = bb[s][ct].y;
        sc[ct][0] = __expf(fmaf(sc[ct][0], 0.125f, __uint_as_float(ux << 16)));
        sc[ct][1] = __expf(fmaf(sc[ct][1], 0.125f, __uint_as_float(ux & 0xFFFF0000u)));
        sc[ct][2] = __expf(fmaf(sc[ct][2], 0.125f, __uint_as_float(uy << 16)));
        sc[ct][3] = __expf(fmaf(sc[ct][3], 0.125f, __uint_as_float(uy & 0xFFFF0000u)));
        ls[s] += sc[ct][0] + sc[ct][1] + sc[ct][2] + sc[ct][3];
        // pack 4 consecutive keys -> one b64 in P A-frag layout (verified R6)
        const int h  = (4 * ct + Q) >> 3;
        const int o  = (2 * ct + (Q >> 1)) & 3;
        const int j0 = (Q & 1) * 4;
        const unsigned long long u =
            (unsigned long long)pack_rtz(sc[ct][0], sc[ct][1]) |
            ((unsigned long long)pack_rtz(sc[ct][2], sc[ct][3]) << 32);
        *(unsigned long long*)&PT[w][s][h * 512 + (c + 16 * o) * 8 + j0] = u;
      }
    }

    short8 vf[8];
#pragma unroll
    for (int f = 0; f < 8; ++f)
      vf[f] = *(const short8*)&Vf[p][f * 512 + lane * 8];
#pragma unroll
    for (int s = 0; s < 2; ++s) {
      const short8 pa0 = *(const short8*)&PT[w][s][lane * 8];
      const short8 pa1 = *(const short8*)&PT[w][s][512 + lane * 8];
#pragma unroll
      for (int dt = 0; dt < 4; ++dt) {
        oc[s][dt] = MFMA_BF16(pa0, vf[dt * 2 + 0], oc[s][dt]);
        oc[s][dt] = MFMA_BF16(pa1, vf[dt * 2 + 1], oc[s][dt]);
      }
    }
    __syncthreads();   // readers of buf p done; drains prefetch (K/V + bias regs)
#pragma unroll
    for (int s = 0; s < 2; ++s)
#pragma unroll
      for (int ct = 0; ct < 4; ++ct) bb[s][ct] = bn[s][ct];
  }

  // lsum: per-lane partial is for q=c; reduce across quads, redistribute to rows
#pragma unroll
  for (int s = 0; s < 2; ++s) {
    float v = ls[s];
    v += __shfl_xor(v, 16);
    v += __shfl_xor(v, 32);
    ls[s] = v;
  }
#pragma unroll
  for (int s = 0; s < 2; ++s) {
    float inv[4];
#pragma unroll
    for (int r = 0; r < 4; ++r)
      inv[r] = __builtin_amdgcn_rcpf(__shfl(ls[s], Q * 4 + r));
#pragma unroll
    for (int dt = 0; dt < 4; ++dt) {
      const float bo = bout[goff + dt * 16 + c];
#pragma unroll
      for (int r = 0; r < 4; ++r)
        Out[(size_t)(qw + s * 16 + Q * 4 + r) * CDIM + goff + dt * 16 + c] =
            oc[s][dt][r] * inv[r] + bo;
    }
  }
}

extern "C" void kernel_launch(void* const* d_in, const int* in_sizes, int n_in,
                              void* d_out, int out_size, void* d_ws, size_t ws_size,
                              hipStream_t stream) {
  const float* in_x = (const float*)d_in[0];
  const float* rois = (const float*)d_in[1];
  const float* W0   = (const float*)d_in[2];
  const float* b0   = (const float*)d_in[3];
  const float* W1   = (const float*)d_in[4];
  const float* b1   = (const float*)d_in[5];
  const float* Wout = (const float*)d_in[6];  // (G,D,C) flat == (C,C) row-major
  const float* bout = (const float*)d_in[7];
  char* w8 = (char*)d_ws;

  // ws layout (22 MB):
  //   [0,4M)   xin_b (bf16 x) -> xb (gemm1 out; xin_b dead after gemm_fused)
  //   [4,6M)   W0b   [6,8M) W1b   [8,10M) Woutb
  //   [10,14M) zT (bf16 V^T)
  //   [14,22M) biasln (bf16 ln(iou+1e-6))
  // t0b (bf16 gemm0 out) lives in d_out; attn overwrites d_out with final fp32.
  short* xin_b = (short*)w8;
  short* W0b   = (short*)(w8 + ((size_t)4 << 20));
  short* W1b   = (short*)(w8 + ((size_t)6 << 20));
  short* Woutb = (short*)(w8 + ((size_t)8 << 20));
  short* zT    = (short*)(w8 + ((size_t)10 << 20));
  unsigned short* biasln = (unsigned short*)(w8 + ((size_t)14 << 20));
  short* xb  = xin_b;
  short* t0b = (short*)d_out;

  // 1) conversions + ln-iou bias
  conv_iou<<<2048 + 16384, 256, 0, stream>>>(in_x, W0, W1, Wout, rois,
                                             xin_b, W0b, W1b, Woutb, biasln);
  // 2) double-buffered fused 128x128: t0 = relu(x)@W0^T+b0 and zT = (x@Wout^T)^T
  gemm_fused<<<dim3(16, 16), 256, 0, stream>>>(xin_b, W0b, Woutb, b0, t0b, zT);
  // 3) double-buffered 128x64: xb = relu(t0)@W1^T + b1
  gemm1k<<<dim3(16, 16), 256, 0, stream>>>(t0b, W1b, b1, xb);
  // 4) flash attention (K-major S', coop dbuf staging)
  attn3<<<dim3(NROI / 128, NG), 256, 0, stream>>>(xb, zT, biasln, bout,
                                                  (float*)d_out);
}

// Round 8
// 192.546 us; speedup vs baseline: 1.4274x; 1.1624x over previous
//
#include <hip/hip_runtime.h>
#include <math.h>

// Problem constants
constexpr int NROI = 2048;  // N
constexpr int CDIM = 1024;  // C
constexpr int NG   = 16;    // groups
constexpr int DH   = 64;    // per-group dim

typedef __attribute__((ext_vector_type(8))) short short8;    // 8 bf16 (4 VGPRs)
typedef __attribute__((ext_vector_type(4))) float floatx4;   // MFMA C/D frag

#define MFMA_BF16(a, b, c) __builtin_amdgcn_mfma_f32_16x16x32_bf16((a), (b), (c), 0, 0, 0)

// fp32 -> bf16 round-to-nearest-even
__device__ __forceinline__ short f2bf(float f) {
  unsigned u = __float_as_uint(f);
  unsigned r = 0x7fffu + ((u >> 16) & 1u);
  return (short)((u + r) >> 16);
}
__device__ __forceinline__ float bf2f(unsigned short u) {
  return __uint_as_float(((unsigned)u) << 16);
}
__device__ __forceinline__ unsigned pack2(float a, float b) {
  return (unsigned)(unsigned short)f2bf(a) | ((unsigned)(unsigned short)f2bf(b) << 16);
}

// async global->LDS, 16B per lane; LDS dest = wave-uniform base + lane*16
typedef __attribute__((address_space(1))) void GV;
typedef __attribute__((address_space(3))) void LV;
__device__ __forceinline__ void gl2lds16(const void* g, void* l) {
  __builtin_amdgcn_global_load_lds((GV*)g, (LV*)l, 16, 0, 0);
}

// bf16 relu on a packed short8 (sign-bit based; exact)
__device__ __forceinline__ short8 brelu(short8 v) {
  union { short8 s; unsigned u[4]; } x; x.s = v;
#pragma unroll
  for (int i = 0; i < 4; ++i) {
    unsigned m = (x.u[i] >> 15) & 0x10001u;
    x.u[i] &= ~(m * 0xFFFFu);
  }
  return x.s;
}

// ---------------- streaming fp32 -> bf16 conversion (x + 3 weights) ----------------
__global__ __launch_bounds__(256) void convert_kernel(
    const float* __restrict__ in_x, const float* __restrict__ W0,
    const float* __restrict__ W1, const float* __restrict__ Wout,
    short* __restrict__ xin_b, short* __restrict__ W0b,
    short* __restrict__ W1b, short* __restrict__ Woutb)
{
  const int i = blockIdx.x * 256 + threadIdx.x;   // float4 units
  {
    const float4 v = ((const float4*)in_x)[i];
    uint2 u; u.x = pack2(v.x, v.y); u.y = pack2(v.z, v.w);
    ((uint2*)xin_b)[i] = u;
  }
  if (i < 262144) {
    float4 v = ((const float4*)W0)[i];
    uint2 u; u.x = pack2(v.x, v.y); u.y = pack2(v.z, v.w);
    ((uint2*)W0b)[i] = u;
    v = ((const float4*)W1)[i];
    u.x = pack2(v.x, v.y); u.y = pack2(v.z, v.w);
    ((uint2*)W1b)[i] = u;
    v = ((const float4*)Wout)[i];
    u.x = pack2(v.x, v.y); u.y = pack2(v.z, v.w);
    ((uint2*)Woutb)[i] = u;
  }
}

// ---------------- iou+1e-6 matrix, 4 keys/thread, rcp divide, 8-B stores ----------------
__global__ __launch_bounds__(256) void iou4_kernel(const float* __restrict__ rois,
                                                   unsigned short* __restrict__ biasb)
{
  const int q  = blockIdx.y;
  const int k0 = (blockIdx.x * 256 + threadIdx.x) * 4;
  const float qx1 = rois[q * 5 + 1], qy1 = rois[q * 5 + 2];
  const float qx2 = rois[q * 5 + 3], qy2 = rois[q * 5 + 4];
  const float qa = (qx2 - qx1 + 1.f) * (qy2 - qy1 + 1.f);
  float v[4];
#pragma unroll
  for (int j = 0; j < 4; ++j) {
    const int k = k0 + j;
    const float kx1 = rois[k * 5 + 1], ky1 = rois[k * 5 + 2];
    const float kx2 = rois[k * 5 + 3], ky2 = rois[k * 5 + 4];
    const float ka = (kx2 - kx1 + 1.f) * (ky2 - ky1 + 1.f);
    float iw = fminf(qx2, kx2) - fmaxf(qx1, kx1) + 1.f;
    float ih = fminf(qy2, ky2) - fmaxf(qy1, ky1) + 1.f;
    iw = fmaxf(iw, 0.f); ih = fmaxf(ih, 0.f);
    const float inter = iw * ih;
    // rcp-based divide: rel err ~1e-5, invisible after bf16 round (0.4%)
    v[j] = inter * __builtin_amdgcn_rcpf(qa + ka - inter) + 1e-6f;
  }
  uint2 u; u.x = pack2(v[0], v[1]); u.y = pack2(v[2], v[3]);
  *(uint2*)&biasb[(size_t)q * NROI + k0] = u;
}

// ---------------- double-buffered 128x128 fused GEMM (GEMM0 + GEMM2) ----------------
// blockIdx.x < 8: t0 = relu(x)@W0^T + b0 (row-major bf16 out).
// blockIdx.x >= 8: zT = (x@Wout^T)^T (bf16, C x N).
__global__ __launch_bounds__(256) void gemm_fused(
    const short* __restrict__ A, const short* __restrict__ BW0,
    const short* __restrict__ BWout, const float* __restrict__ b0,
    short* __restrict__ t0b, short* __restrict__ zT)
{
  __shared__ short As[2][16 * 512];
  __shared__ short Bs[2][16 * 512];
  const int t = threadIdx.x, w = t >> 6, lane = t & 63;
  const int wm = w >> 1, wn = w & 1;
  const int row0 = blockIdx.y * 128;
  const int bx = blockIdx.x;
  const bool isW0 = bx < 8;
  const int col0 = (bx & 7) * 128;
  const short* B = isW0 ? BW0 : BWout;
  const int rlo = lane & 15, khi = (lane >> 4) * 8;

  floatx4 acc[4][4];
#pragma unroll
  for (int i = 0; i < 4; ++i)
#pragma unroll
    for (int j = 0; j < 4; ++j) acc[i][j] = (floatx4){0.f, 0.f, 0.f, 0.f};

#pragma unroll
  for (int q = 0; q < 4; ++q) {
    const int f = w * 4 + q, rt = f >> 1, kh = f & 1;
    gl2lds16(A + (size_t)(row0 + rt * 16 + rlo) * CDIM + kh * 32 + khi, &As[0][f * 512]);
    gl2lds16(B + (size_t)(col0 + rt * 16 + rlo) * CDIM + kh * 32 + khi, &Bs[0][f * 512]);
  }
  __syncthreads();

  for (int it = 0; it < 16; ++it) {
    const int p = it & 1;
    if (it < 15) {
      const int k1 = (it + 1) * 64;
#pragma unroll
      for (int q = 0; q < 4; ++q) {
        const int f = w * 4 + q, rt = f >> 1, kh = f & 1;
        gl2lds16(A + (size_t)(row0 + rt * 16 + rlo) * CDIM + k1 + kh * 32 + khi,
                 &As[1 - p][f * 512]);
        gl2lds16(B + (size_t)(col0 + rt * 16 + rlo) * CDIM + k1 + kh * 32 + khi,
                 &Bs[1 - p][f * 512]);
      }
    }
#pragma unroll
    for (int kh = 0; kh < 2; ++kh) {
      short8 a[4], bf[4];
#pragma unroll
      for (int i = 0; i < 4; ++i) {
        a[i] = *(const short8*)&As[p][((wm * 4 + i) * 2 + kh) * 512 + lane * 8];
        if (isW0) a[i] = brelu(a[i]);
      }
#pragma unroll
      for (int j = 0; j < 4; ++j)
        bf[j] = *(const short8*)&Bs[p][((wn * 4 + j) * 2 + kh) * 512 + lane * 8];
#pragma unroll
      for (int i = 0; i < 4; ++i)
#pragma unroll
        for (int j = 0; j < 4; ++j)
          acc[i][j] = MFMA_BF16(a[i], bf[j], acc[i][j]);
    }
    __syncthreads();
  }

  const int colL = lane & 15, qq = lane >> 4;
  if (isW0) {
    float bj[4];
#pragma unroll
    for (int j = 0; j < 4; ++j) bj[j] = b0[col0 + wn * 64 + j * 16 + colL];
#pragma unroll
    for (int i = 0; i < 4; ++i)
#pragma unroll
      for (int j = 0; j < 4; ++j)
#pragma unroll
        for (int r = 0; r < 4; ++r) {
          const int row = row0 + wm * 64 + i * 16 + qq * 4 + r;
          const int cc  = col0 + wn * 64 + j * 16 + colL;
          t0b[(size_t)row * CDIM + cc] = f2bf(acc[i][j][r] + bj[j]);
        }
  } else {
#pragma unroll
    for (int i = 0; i < 4; ++i)
#pragma unroll
      for (int j = 0; j < 4; ++j) {
        unsigned long long u =
            (unsigned long long)pack2(acc[i][j][0], acc[i][j][1]) |
            ((unsigned long long)pack2(acc[i][j][2], acc[i][j][3]) << 32);
        const int cc  = col0 + wn * 64 + j * 16 + colL;
        const int row = row0 + wm * 64 + i * 16 + qq * 4;
        *(unsigned long long*)&zT[(size_t)cc * NROI + row] = u;
      }
  }
}

// ---------------- double-buffered 128x64 GEMM1: xb = relu(t0) @ W1^T + b1 ----------------
__global__ __launch_bounds__(256) void gemm1k(
    const short* __restrict__ A, const short* __restrict__ B,
    const float* __restrict__ bias, short* __restrict__ C)
{
  __shared__ short As[2][16 * 512];
  __shared__ short Bs[2][8 * 512];
  const int t = threadIdx.x, w = t >> 6, lane = t & 63;
  const int wm = w >> 1, wn = w & 1;
  const int row0 = blockIdx.y * 128, col0 = blockIdx.x * 64;
  const int rlo = lane & 15, khi = (lane >> 4) * 8;

  floatx4 acc[4][2];
#pragma unroll
  for (int i = 0; i < 4; ++i)
#pragma unroll
    for (int j = 0; j < 2; ++j) acc[i][j] = (floatx4){0.f, 0.f, 0.f, 0.f};

#pragma unroll
  for (int q = 0; q < 4; ++q) {
    const int f = w * 4 + q, rt = f >> 1, kh = f & 1;
    gl2lds16(A + (size_t)(row0 + rt * 16 + rlo) * CDIM + kh * 32 + khi, &As[0][f * 512]);
  }
#pragma unroll
  for (int q = 0; q < 2; ++q) {
    const int f = w * 2 + q, rt = f >> 1, kh = f & 1;
    gl2lds16(B + (size_t)(col0 + rt * 16 + rlo) * CDIM + kh * 32 + khi, &Bs[0][f * 512]);
  }
  __syncthreads();

  for (int it = 0; it < 16; ++it) {
    const int p = it & 1;
    if (it < 15) {
      const int k1 = (it + 1) * 64;
#pragma unroll
      for (int q = 0; q < 4; ++q) {
        const int f = w * 4 + q, rt = f >> 1, kh = f & 1;
        gl2lds16(A + (size_t)(row0 + rt * 16 + rlo) * CDIM + k1 + kh * 32 + khi,
                 &As[1 - p][f * 512]);
      }
#pragma unroll
      for (int q = 0; q < 2; ++q) {
        const int f = w * 2 + q, rt = f >> 1, kh = f & 1;
        gl2lds16(B + (size_t)(col0 + rt * 16 + rlo) * CDIM + k1 + kh * 32 + khi,
                 &Bs[1 - p][f * 512]);
      }
    }
#pragma unroll
    for (int kh = 0; kh < 2; ++kh) {
      short8 a[4], bf[2];
#pragma unroll
      for (int i = 0; i < 4; ++i)
        a[i] = brelu(*(const short8*)&As[p][((wm * 4 + i) * 2 + kh) * 512 + lane * 8]);
#pragma unroll
      for (int j = 0; j < 2; ++j)
        bf[j] = *(const short8*)&Bs[p][((wn * 2 + j) * 2 + kh) * 512 + lane * 8];
#pragma unroll
      for (int i = 0; i < 4; ++i)
#pragma unroll
        for (int j = 0; j < 2; ++j)
          acc[i][j] = MFMA_BF16(a[i], bf[j], acc[i][j]);
    }
    __syncthreads();
  }

  const int colL = lane & 15, qq = lane >> 4;
  float bj[2];
  bj[0] = bias[col0 + wn * 32 + colL];
  bj[1] = bias[col0 + wn * 32 + 16 + colL];
#pragma unroll
  for (int i = 0; i < 4; ++i)
#pragma unroll
    for (int j = 0; j < 2; ++j)
#pragma unroll
      for (int r = 0; r < 4; ++r) {
        const int row = row0 + wm * 64 + i * 16 + qq * 4 + r;
        const int cc  = col0 + wn * 32 + j * 16 + colL;
        C[(size_t)row * CDIM + cc] = f2bf(acc[i][j][r] + bj[j]);
      }
}

// ---------------- MFMA flash attention (R3-verified 54.5 us version, verbatim) ----------------
// P = exp(s/8) * (iou+1e-6); no running max. 512 thr = 8 waves = 128 q/block;
// K/V double-buffered via global_load_lds; bias loaded per-iteration (scalar 2B,
// issued early, overlapped by QK MFMAs).
__global__ __launch_bounds__(512) void attn_bias(
    const short* __restrict__ Xb,             // (N,C) bf16 embedded x
    const short* __restrict__ ZTb,            // (C,N) bf16 V, transposed
    const unsigned short* __restrict__ biasb, // (N,N) bf16 iou+1e-6
    const float* __restrict__ bout,
    float* __restrict__ Out)
{
  const int g  = blockIdx.y;
  const int n0 = blockIdx.x * 128;
  const int t  = threadIdx.x;
  const int w    = t >> 6;
  const int lane = t & 63;
  const int col  = lane & 15;
  const int qq   = lane >> 4;
  const int t16 = (w >> 1) * 16;
  const int h32 = (w & 1) * 32;
  const int rlo = lane & 15, khi = (lane >> 4) * 8;

  __shared__ short Kf[2][8 * 512];
  __shared__ short Vf[2][8 * 512];
  __shared__ short Pf[8 * 1024];

  const size_t qoff = (size_t)(n0 + w * 16 + col) * CDIM + g * DH;
  const short8 qf0 = *(const short8*)(Xb + qoff + qq * 8);
  const short8 qf1 = *(const short8*)(Xb + qoff + 32 + qq * 8);

  floatx4 oc[4];
#pragma unroll
  for (int dt = 0; dt < 4; ++dt) oc[dt] = (floatx4){0.f, 0.f, 0.f, 0.f};
  float lsum[4] = {0.f, 0.f, 0.f, 0.f};

  gl2lds16(Xb + (size_t)(t16 + rlo) * CDIM + g * DH + h32 + khi, &Kf[0][w * 512]);
  gl2lds16(ZTb + (size_t)(g * DH + t16 + rlo) * NROI + h32 + khi, &Vf[0][w * 512]);
  __syncthreads();

  for (int it = 0; it < NROI / 64; ++it) {
    const int p  = it & 1;
    const int m0 = it * 64;
    if (it + 1 < NROI / 64) {
      const int m1 = m0 + 64;
      gl2lds16(Xb + (size_t)(m1 + t16 + rlo) * CDIM + g * DH + h32 + khi,
               &Kf[1 - p][w * 512]);
      gl2lds16(ZTb + (size_t)(g * DH + t16 + rlo) * NROI + m1 + h32 + khi,
               &Vf[1 - p][w * 512]);
    }

    float bb[4][4];
#pragma unroll
    for (int ct = 0; ct < 4; ++ct)
#pragma unroll
      for (int r = 0; r < 4; ++r)
        bb[ct][r] = bf2f(biasb[(size_t)(n0 + w * 16 + qq * 4 + r) * NROI +
                               m0 + ct * 16 + col]);

    floatx4 sc[4];
#pragma unroll
    for (int ct = 0; ct < 4; ++ct) {
      const short8 b0 = *(const short8*)&Kf[p][(ct * 2 + 0) * 512 + lane * 8];
      const short8 b1 = *(const short8*)&Kf[p][(ct * 2 + 1) * 512 + lane * 8];
      floatx4 z4 = (floatx4){0.f, 0.f, 0.f, 0.f};
      z4 = MFMA_BF16(qf0, b0, z4);
      z4 = MFMA_BF16(qf1, b1, z4);
      sc[ct] = z4;
    }

#pragma unroll
    for (int ct = 0; ct < 4; ++ct)
#pragma unroll
      for (int r = 0; r < 4; ++r)
        sc[ct][r] = __expf(sc[ct][r] * 0.125f) * bb[ct][r];
#pragma unroll
    for (int r = 0; r < 4; ++r)
      lsum[r] += sc[0][r] + sc[1][r] + sc[2][r] + sc[3][r];

    {
      short* pw = &Pf[w * 1024];
#pragma unroll
      for (int ct = 0; ct < 4; ++ct) {
        const int key = ct * 16 + col;
        const int base = (key >> 5) * 512 + (key & 7);
#pragma unroll
        for (int r = 0; r < 4; ++r) {
          const int dl = (4 * qq + r) + ((key >> 3) & 3) * 16;
          pw[base + dl * 8] = f2bf(sc[ct][r]);
        }
      }
      const short8 pa0 = *(const short8*)&pw[0 * 512 + lane * 8];
      const short8 pa1 = *(const short8*)&pw[1 * 512 + lane * 8];
#pragma unroll
      for (int dt = 0; dt < 4; ++dt) {
        const short8 v0 = *(const short8*)&Vf[p][(dt * 2 + 0) * 512 + lane * 8];
        const short8 v1 = *(const short8*)&Vf[p][(dt * 2 + 1) * 512 + lane * 8];
        oc[dt] = MFMA_BF16(pa0, v0, oc[dt]);
        oc[dt] = MFMA_BF16(pa1, v1, oc[dt]);
      }
    }
    __syncthreads();
  }

#pragma unroll
  for (int r = 0; r < 4; ++r) {
    float s = lsum[r];
    s += __shfl_xor(s, 1); s += __shfl_xor(s, 2);
    s += __shfl_xor(s, 4); s += __shfl_xor(s, 8);
    lsum[r] = s;
  }
#pragma unroll
  for (int dt = 0; dt < 4; ++dt) {
    const float bo = bout[g * DH + dt * 16 + col];
#pragma unroll
    for (int r = 0; r < 4; ++r)
      Out[(size_t)(n0 + w * 16 + qq * 4 + r) * CDIM + g * DH + dt * 16 + col] =
          oc[dt][r] / lsum[r] + bo;
  }
}

extern "C" void kernel_launch(void* const* d_in, const int* in_sizes, int n_in,
                              void* d_out, int out_size, void* d_ws, size_t ws_size,
                              hipStream_t stream) {
  const float* in_x = (const float*)d_in[0];
  const float* rois = (const float*)d_in[1];
  const float* W0   = (const float*)d_in[2];
  const float* b0   = (const float*)d_in[3];
  const float* W1   = (const float*)d_in[4];
  const float* b1   = (const float*)d_in[5];
  const float* Wout = (const float*)d_in[6];  // (G,D,C) flat == (C,C) row-major
  const float* bout = (const float*)d_in[7];
  char* w8 = (char*)d_ws;

  // ws layout (22 MB):
  //   [0,4M)   xin_b (bf16 x) -> xb (gemm1 out; xin_b dead after gemm_fused)
  //   [4,6M)   W0b   [6,8M) W1b   [8,10M) Woutb
  //   [10,14M) zT (bf16 V^T)
  //   [14,22M) biasb (bf16 iou+1e-6)
  // t0b (bf16 gemm0 out) lives in d_out; attn overwrites d_out with final fp32.
  short* xin_b = (short*)w8;
  short* W0b   = (short*)(w8 + ((size_t)4 << 20));
  short* W1b   = (short*)(w8 + ((size_t)6 << 20));
  short* Woutb = (short*)(w8 + ((size_t)8 << 20));
  short* zT    = (short*)(w8 + ((size_t)10 << 20));
  unsigned short* biasb = (unsigned short*)(w8 + ((size_t)14 << 20));
  short* xb  = xin_b;
  short* t0b = (short*)d_out;

  // 1) streaming converts
  convert_kernel<<<2048, 256, 0, stream>>>(in_x, W0, W1, Wout,
                                           xin_b, W0b, W1b, Woutb);
  // 2) iou bias matrix (4 keys/thread, rcp divide, vectorized stores)
  iou4_kernel<<<dim3(2, NROI), 256, 0, stream>>>(rois, biasb);
  // 3) double-buffered fused 128x128: t0 = relu(x)@W0^T+b0 and zT = (x@Wout^T)^T
  gemm_fused<<<dim3(16, 16), 256, 0, stream>>>(xin_b, W0b, Woutb, b0, t0b, zT);
  // 4) double-buffered 128x64: xb = relu(t0)@W1^T + b1
  gemm1k<<<dim3(16, 16), 256, 0, stream>>>(t0b, W1b, b1, xb);
  // 5) flash attention (R3-verified)
  attn_bias<<<dim3(NROI / 128, NG), 512, 0, stream>>>(xb, zT, biasb, bout,
                                                      (float*)d_out);
}

// Round 9
// 187.550 us; speedup vs baseline: 1.4654x; 1.0266x over previous
//
#include <hip/hip_runtime.h>
#include <math.h>

// Problem constants
constexpr int NROI = 2048;  // N
constexpr int CDIM = 1024;  // C
constexpr int NG   = 16;    // groups
constexpr int DH   = 64;    // per-group dim

typedef __attribute__((ext_vector_type(8))) short short8;    // 8 bf16 (4 VGPRs)
typedef __attribute__((ext_vector_type(4))) float floatx4;   // MFMA C/D frag

#define MFMA_BF16(a, b, c) __builtin_amdgcn_mfma_f32_16x16x32_bf16((a), (b), (c), 0, 0, 0)

// fp32 -> bf16 round-to-nearest-even
__device__ __forceinline__ short f2bf(float f) {
  unsigned u = __float_as_uint(f);
  unsigned r = 0x7fffu + ((u >> 16) & 1u);
  return (short)((u + r) >> 16);
}
__device__ __forceinline__ float bf2f(unsigned short u) {
  return __uint_as_float(((unsigned)u) << 16);
}
__device__ __forceinline__ unsigned pack2(float a, float b) {
  return (unsigned)(unsigned short)f2bf(a) | ((unsigned)(unsigned short)f2bf(b) << 16);
}

// async global->LDS, 16B per lane; LDS dest = wave-uniform base + lane*16
typedef __attribute__((address_space(1))) void GV;
typedef __attribute__((address_space(3))) void LV;
__device__ __forceinline__ void gl2lds16(const void* g, void* l) {
  __builtin_amdgcn_global_load_lds((GV*)g, (LV*)l, 16, 0, 0);
}

// bf16 relu on a packed short8 (sign-bit based; exact)
__device__ __forceinline__ short8 brelu(short8 v) {
  union { short8 s; unsigned u[4]; } x; x.s = v;
#pragma unroll
  for (int i = 0; i < 4; ++i) {
    unsigned m = (x.u[i] >> 15) & 0x10001u;
    x.u[i] &= ~(m * 0xFFFFu);
  }
  return x.s;
}

// ---------------- streaming fp32 -> bf16 conversion (x + 3 weights) ----------------
__global__ __launch_bounds__(256) void convert_kernel(
    const float* __restrict__ in_x, const float* __restrict__ W0,
    const float* __restrict__ W1, const float* __restrict__ Wout,
    short* __restrict__ xin_b, short* __restrict__ W0b,
    short* __restrict__ W1b, short* __restrict__ Woutb)
{
  const int i = blockIdx.x * 256 + threadIdx.x;   // float4 units
  {
    const float4 v = ((const float4*)in_x)[i];
    uint2 u; u.x = pack2(v.x, v.y); u.y = pack2(v.z, v.w);
    ((uint2*)xin_b)[i] = u;
  }
  if (i < 262144) {
    float4 v = ((const float4*)W0)[i];
    uint2 u; u.x = pack2(v.x, v.y); u.y = pack2(v.z, v.w);
    ((uint2*)W0b)[i] = u;
    v = ((const float4*)W1)[i];
    u.x = pack2(v.x, v.y); u.y = pack2(v.z, v.w);
    ((uint2*)W1b)[i] = u;
    v = ((const float4*)Wout)[i];
    u.x = pack2(v.x, v.y); u.y = pack2(v.z, v.w);
    ((uint2*)Woutb)[i] = u;
  }
}

// ---------------- iou+1e-6 matrix, 4 keys/thread, rcp divide, 8-B stores ----------------
__global__ __launch_bounds__(256) void iou4_kernel(const float* __restrict__ rois,
                                                   unsigned short* __restrict__ biasb)
{
  const int q  = blockIdx.y;
  const int k0 = (blockIdx.x * 256 + threadIdx.x) * 4;
  const float qx1 = rois[q * 5 + 1], qy1 = rois[q * 5 + 2];
  const float qx2 = rois[q * 5 + 3], qy2 = rois[q * 5 + 4];
  const float qa = (qx2 - qx1 + 1.f) * (qy2 - qy1 + 1.f);
  float v[4];
#pragma unroll
  for (int j = 0; j < 4; ++j) {
    const int k = k0 + j;
    const float kx1 = rois[k * 5 + 1], ky1 = rois[k * 5 + 2];
    const float kx2 = rois[k * 5 + 3], ky2 = rois[k * 5 + 4];
    const float ka = (kx2 - kx1 + 1.f) * (ky2 - ky1 + 1.f);
    float iw = fminf(qx2, kx2) - fmaxf(qx1, kx1) + 1.f;
    float ih = fminf(qy2, ky2) - fmaxf(qy1, ky1) + 1.f;
    iw = fmaxf(iw, 0.f); ih = fmaxf(ih, 0.f);
    const float inter = iw * ih;
    v[j] = inter * __builtin_amdgcn_rcpf(qa + ka - inter) + 1e-6f;
  }
  uint2 u; u.x = pack2(v[0], v[1]); u.y = pack2(v[2], v[3]);
  *(uint2*)&biasb[(size_t)q * NROI + k0] = u;
}

// ---------------- 64x64 double-buffered GEMM, high occupancy ----------------
// FUSED=1: blockIdx.x<16 -> t0 = relu(x)@W0^T+b0 (row-major); else
//          zT = (x@Wout^T)^T (transposed out). grid (32,32) = 1024 blocks = 4/CU.
// FUSED=0: C = relu(A)@B^T + bias (row-major). grid (16,32) = 512 = 2/CU.
// 4 waves; wave quadrant 32x32 (acc 2x2 frags). LDS 32 KB -> 4 blocks/CU.
template <int FUSED>
__global__ __launch_bounds__(256, 4) void gemm64(
    const short* __restrict__ A, const short* __restrict__ Ba,
    const short* __restrict__ Bb, const float* __restrict__ bias,
    short* __restrict__ outRM, short* __restrict__ outTR)
{
  __shared__ short As[2][8 * 512];
  __shared__ short Bs[2][8 * 512];
  const int t = threadIdx.x, w = t >> 6, lane = t & 63;
  const int wm = w >> 1, wn = w & 1;
  const int row0 = blockIdx.y * 64;
  bool isW0; int col0; const short* B;
  if (FUSED) {
    isW0 = blockIdx.x < 16;
    col0 = (blockIdx.x & 15) * 64;
    B = isW0 ? Ba : Bb;
  } else {
    isW0 = true; col0 = blockIdx.x * 64; B = Ba;
  }
  const bool doRelu = FUSED ? isW0 : true;
  const int rlo = lane & 15, khi = (lane >> 4) * 8;

  floatx4 acc[2][2];
#pragma unroll
  for (int i = 0; i < 2; ++i)
#pragma unroll
    for (int j = 0; j < 2; ++j) acc[i][j] = (floatx4){0.f, 0.f, 0.f, 0.f};

  // stage k=0: wave w stages A frags {2w,2w+1} (row-tile w, both k-halves), same for B
#pragma unroll
  for (int kh = 0; kh < 2; ++kh) {
    const int f = w * 2 + kh;
    gl2lds16(A + (size_t)(row0 + w * 16 + rlo) * CDIM + kh * 32 + khi, &As[0][f * 512]);
    gl2lds16(B + (size_t)(col0 + w * 16 + rlo) * CDIM + kh * 32 + khi, &Bs[0][f * 512]);
  }
  __syncthreads();

  for (int it = 0; it < 16; ++it) {
    const int p = it & 1;
    if (it < 15) {                      // prefetch next K-tile while computing this one
      const int k1 = (it + 1) * 64;
#pragma unroll
      for (int kh = 0; kh < 2; ++kh) {
        const int f = w * 2 + kh;
        gl2lds16(A + (size_t)(row0 + w * 16 + rlo) * CDIM + k1 + kh * 32 + khi,
                 &As[1 - p][f * 512]);
        gl2lds16(B + (size_t)(col0 + w * 16 + rlo) * CDIM + k1 + kh * 32 + khi,
                 &Bs[1 - p][f * 512]);
      }
    }
#pragma unroll
    for (int kh = 0; kh < 2; ++kh) {
      short8 a[2], bf[2];
#pragma unroll
      for (int i = 0; i < 2; ++i) {
        a[i] = *(const short8*)&As[p][((wm * 2 + i) * 2 + kh) * 512 + lane * 8];
        if (doRelu) a[i] = brelu(a[i]);
      }
#pragma unroll
      for (int j = 0; j < 2; ++j)
        bf[j] = *(const short8*)&Bs[p][((wn * 2 + j) * 2 + kh) * 512 + lane * 8];
#pragma unroll
      for (int i = 0; i < 2; ++i)
#pragma unroll
        for (int j = 0; j < 2; ++j)
          acc[i][j] = MFMA_BF16(a[i], bf[j], acc[i][j]);
    }
    __syncthreads();   // readers of buf p done; drains prefetch into buf 1-p
  }

  const int colL = lane & 15, qq = lane >> 4;
  if (!FUSED || isW0) {
    float bj[2];
    bj[0] = bias[col0 + wn * 32 + colL];
    bj[1] = bias[col0 + wn * 32 + 16 + colL];
#pragma unroll
    for (int i = 0; i < 2; ++i)
#pragma unroll
      for (int j = 0; j < 2; ++j)
#pragma unroll
        for (int r = 0; r < 4; ++r) {
          const int row = row0 + wm * 32 + i * 16 + qq * 4 + r;
          const int cc  = col0 + wn * 32 + j * 16 + colL;
          outRM[(size_t)row * CDIM + cc] = f2bf(acc[i][j][r] + bj[j]);
        }
  } else {
#pragma unroll
    for (int i = 0; i < 2; ++i)
#pragma unroll
      for (int j = 0; j < 2; ++j) {
        unsigned long long u =
            (unsigned long long)pack2(acc[i][j][0], acc[i][j][1]) |
            ((unsigned long long)pack2(acc[i][j][2], acc[i][j][3]) << 32);
        const int cc  = col0 + wn * 32 + j * 16 + colL;
        const int row = row0 + wm * 32 + i * 16 + qq * 4;
        *(unsigned long long*)&outTR[(size_t)cc * NROI + row] = u;
      }
  }
}

// ---------------- MFMA flash attention (R3-verified 54.5 us version, verbatim) ----------------
// P = exp(s/8) * (iou+1e-6); no running max. 512 thr = 8 waves = 128 q/block;
// K/V double-buffered via global_load_lds; bias loaded per-iteration.
__global__ __launch_bounds__(512) void attn_bias(
    const short* __restrict__ Xb,             // (N,C) bf16 embedded x
    const short* __restrict__ ZTb,            // (C,N) bf16 V, transposed
    const unsigned short* __restrict__ biasb, // (N,N) bf16 iou+1e-6
    const float* __restrict__ bout,
    float* __restrict__ Out)
{
  const int g  = blockIdx.y;
  const int n0 = blockIdx.x * 128;
  const int t  = threadIdx.x;
  const int w    = t >> 6;
  const int lane = t & 63;
  const int col  = lane & 15;
  const int qq   = lane >> 4;
  const int t16 = (w >> 1) * 16;
  const int h32 = (w & 1) * 32;
  const int rlo = lane & 15, khi = (lane >> 4) * 8;

  __shared__ short Kf[2][8 * 512];
  __shared__ short Vf[2][8 * 512];
  __shared__ short Pf[8 * 1024];

  const size_t qoff = (size_t)(n0 + w * 16 + col) * CDIM + g * DH;
  const short8 qf0 = *(const short8*)(Xb + qoff + qq * 8);
  const short8 qf1 = *(const short8*)(Xb + qoff + 32 + qq * 8);

  floatx4 oc[4];
#pragma unroll
  for (int dt = 0; dt < 4; ++dt) oc[dt] = (floatx4){0.f, 0.f, 0.f, 0.f};
  float lsum[4] = {0.f, 0.f, 0.f, 0.f};

  gl2lds16(Xb + (size_t)(t16 + rlo) * CDIM + g * DH + h32 + khi, &Kf[0][w * 512]);
  gl2lds16(ZTb + (size_t)(g * DH + t16 + rlo) * NROI + h32 + khi, &Vf[0][w * 512]);
  __syncthreads();

  for (int it = 0; it < NROI / 64; ++it) {
    const int p  = it & 1;
    const int m0 = it * 64;
    if (it + 1 < NROI / 64) {
      const int m1 = m0 + 64;
      gl2lds16(Xb + (size_t)(m1 + t16 + rlo) * CDIM + g * DH + h32 + khi,
               &Kf[1 - p][w * 512]);
      gl2lds16(ZTb + (size_t)(g * DH + t16 + rlo) * NROI + m1 + h32 + khi,
               &Vf[1 - p][w * 512]);
    }

    float bb[4][4];
#pragma unroll
    for (int ct = 0; ct < 4; ++ct)
#pragma unroll
      for (int r = 0; r < 4; ++r)
        bb[ct][r] = bf2f(biasb[(size_t)(n0 + w * 16 + qq * 4 + r) * NROI +
                               m0 + ct * 16 + col]);

    floatx4 sc[4];
#pragma unroll
    for (int ct = 0; ct < 4; ++ct) {
      const short8 b0 = *(const short8*)&Kf[p][(ct * 2 + 0) * 512 + lane * 8];
      const short8 b1 = *(const short8*)&Kf[p][(ct * 2 + 1) * 512 + lane * 8];
      floatx4 z4 = (floatx4){0.f, 0.f, 0.f, 0.f};
      z4 = MFMA_BF16(qf0, b0, z4);
      z4 = MFMA_BF16(qf1, b1, z4);
      sc[ct] = z4;
    }

#pragma unroll
    for (int ct = 0; ct < 4; ++ct)
#pragma unroll
      for (int r = 0; r < 4; ++r)
        sc[ct][r] = __expf(sc[ct][r] * 0.125f) * bb[ct][r];
#pragma unroll
    for (int r = 0; r < 4; ++r)
      lsum[r] += sc[0][r] + sc[1][r] + sc[2][r] + sc[3][r];

    {
      short* pw = &Pf[w * 1024];
#pragma unroll
      for (int ct = 0; ct < 4; ++ct) {
        const int key = ct * 16 + col;
        const int base = (key >> 5) * 512 + (key & 7);
#pragma unroll
        for (int r = 0; r < 4; ++r) {
          const int dl = (4 * qq + r) + ((key >> 3) & 3) * 16;
          pw[base + dl * 8] = f2bf(sc[ct][r]);
        }
      }
      const short8 pa0 = *(const short8*)&pw[0 * 512 + lane * 8];
      const short8 pa1 = *(const short8*)&pw[1 * 512 + lane * 8];
#pragma unroll
      for (int dt = 0; dt < 4; ++dt) {
        const short8 v0 = *(const short8*)&Vf[p][(dt * 2 + 0) * 512 + lane * 8];
        const short8 v1 = *(const short8*)&Vf[p][(dt * 2 + 1) * 512 + lane * 8];
        oc[dt] = MFMA_BF16(pa0, v0, oc[dt]);
        oc[dt] = MFMA_BF16(pa1, v1, oc[dt]);
      }
    }
    __syncthreads();
  }

#pragma unroll
  for (int r = 0; r < 4; ++r) {
    float s = lsum[r];
    s += __shfl_xor(s, 1); s += __shfl_xor(s, 2);
    s += __shfl_xor(s, 4); s += __shfl_xor(s, 8);
    lsum[r] = s;
  }
#pragma unroll
  for (int dt = 0; dt < 4; ++dt) {
    const float bo = bout[g * DH + dt * 16 + col];
#pragma unroll
    for (int r = 0; r < 4; ++r)
      Out[(size_t)(n0 + w * 16 + qq * 4 + r) * CDIM + g * DH + dt * 16 + col] =
          oc[dt][r] / lsum[r] + bo;
  }
}

extern "C" void kernel_launch(void* const* d_in, const int* in_sizes, int n_in,
                              void* d_out, int out_size, void* d_ws, size_t ws_size,
                              hipStream_t stream) {
  const float* in_x = (const float*)d_in[0];
  const float* rois = (const float*)d_in[1];
  const float* W0   = (const float*)d_in[2];
  const float* b0   = (const float*)d_in[3];
  const float* W1   = (const float*)d_in[4];
  const float* b1   = (const float*)d_in[5];
  const float* Wout = (const float*)d_in[6];  // (G,D,C) flat == (C,C) row-major
  const float* bout = (const float*)d_in[7];
  char* w8 = (char*)d_ws;

  // ws layout (22 MB):
  //   [0,4M)   xin_b (bf16 x) -> xb (gemm1 out; xin_b dead after gemm64<1>)
  //   [4,6M)   W0b   [6,8M) W1b   [8,10M) Woutb
  //   [10,14M) zT (bf16 V^T)
  //   [14,22M) biasb (bf16 iou+1e-6)
  // t0b (bf16 gemm0 out) lives in d_out; attn overwrites d_out with final fp32.
  short* xin_b = (short*)w8;
  short* W0b   = (short*)(w8 + ((size_t)4 << 20));
  short* W1b   = (short*)(w8 + ((size_t)6 << 20));
  short* Woutb = (short*)(w8 + ((size_t)8 << 20));
  short* zT    = (short*)(w8 + ((size_t)10 << 20));
  unsigned short* biasb = (unsigned short*)(w8 + ((size_t)14 << 20));
  short* xb  = xin_b;
  short* t0b = (short*)d_out;

  // 1) streaming converts
  convert_kernel<<<2048, 256, 0, stream>>>(in_x, W0, W1, Wout,
                                           xin_b, W0b, W1b, Woutb);
  // 2) iou bias matrix
  iou4_kernel<<<dim3(2, NROI), 256, 0, stream>>>(rois, biasb);
  // 3) fused 64x64 high-occupancy: t0 = relu(x)@W0^T+b0 and zT = (x@Wout^T)^T
  gemm64<1><<<dim3(32, 32), 256, 0, stream>>>(xin_b, W0b, Woutb, b0, t0b, zT);
  // 4) 64x64 high-occupancy: xb = relu(t0)@W1^T + b1
  gemm64<0><<<dim3(16, 32), 256, 0, stream>>>(t0b, W1b, nullptr, b1, xb, nullptr);
  // 5) flash attention (R3-verified)
  attn_bias<<<dim3(NROI / 128, NG), 512, 0, stream>>>(xb, zT, biasb, bout,
                                                      (float*)d_out);
}